// Round 1
// baseline (70.015 us; speedup 1.0000x reference)
//
#include <hip/hip_runtime.h>
#include <hip/hip_bf16.h>
#include <cstdint>
#include <cstddef>

#define NS 2560
#define NQ 8192
#define NC 512
#define DD 1600

typedef __bf16 bf16_t;
typedef __bf16 bf16x8 __attribute__((ext_vector_type(8)));
typedef float f32x4 __attribute__((ext_vector_type(4)));

// ---------------------------------------------------------------------------
// Kernel 1: class-mean prototypes (bf16) + ||p||^2 (fp32). One block per class.
// ---------------------------------------------------------------------------
__global__ __launch_bounds__(256) void proto_kernel(
    const float* __restrict__ sup, const int* __restrict__ lab,
    bf16_t* __restrict__ protos, float* __restrict__ p2)
{
    const int m   = blockIdx.x;
    const int tid = threadIdx.x;
    __shared__ int   idxs[32];
    __shared__ int   cnt;
    __shared__ float wsum[4];
    if (tid == 0) cnt = 0;
    __syncthreads();
    // cooperative scan for members of class m
    for (int i = tid; i < NS; i += 256) {
        if (lab[i] == m) {
            int p = atomicAdd(&cnt, 1);
            if (p < 32) idxs[p] = i;
        }
    }
    __syncthreads();
    int n = cnt < 32 ? cnt : 32;
    // deterministic order: insertion sort the (tiny) index list
    if (tid == 0 && n > 1) {
        for (int a = 1; a < n; ++a) {
            int key = idxs[a]; int b = a - 1;
            while (b >= 0 && idxs[b] > key) { idxs[b+1] = idxs[b]; --b; }
            idxs[b+1] = key;
        }
    }
    __syncthreads();

    float acc[7];
    #pragma unroll
    for (int u = 0; u < 7; ++u) acc[u] = 0.f;
    for (int t = 0; t < n; ++t) {
        const float* src = sup + (size_t)idxs[t] * DD;
        #pragma unroll
        for (int u = 0; u < 7; ++u) {
            int j = tid + u * 256;
            if (j < DD) acc[u] += src[j];
        }
    }
    float inv = (n > 0) ? 1.f / (float)n : 0.f;
    float psq = 0.f;
    #pragma unroll
    for (int u = 0; u < 7; ++u) {
        int j = tid + u * 256;
        if (j < DD) {
            float p = acc[u] * inv;
            bf16_t pb = (bf16_t)p;          // round once; use rounded value for p2
            protos[(size_t)m * DD + j] = pb;
            float pf = (float)pb;
            psq += pf * pf;
        }
    }
    #pragma unroll
    for (int o = 32; o > 0; o >>= 1) psq += __shfl_xor(psq, o);
    int lane = tid & 63, wid = tid >> 6;
    if (lane == 0) wsum[wid] = psq;
    __syncthreads();
    if (tid == 0) p2[m] = wsum[0] + wsum[1] + wsum[2] + wsum[3];
}

// ---------------------------------------------------------------------------
// Kernel 2: dot[q][c] = sum_k q[q][k] * protos[c][k]  (bf16 MFMA, fp32 acc)
// m97 structure: 128x128 tile, BK=32, 4 waves (2x2), 16x16x32 MFMA.
// A (query, fp32) is reg-staged with fused fp32->bf16 convert; B (protos,
// bf16) staged via global_load_lds dwordx4. K split across blockIdx.z into
// separate partial buffers (summed in the softmax pass).
// ---------------------------------------------------------------------------
__global__ __launch_bounds__(256) void gemm_kernel(
    const float* __restrict__ q, const bf16_t* __restrict__ protos,
    float* __restrict__ spart, int kiters)
{
    __shared__ bf16_t As[128 * 32];
    __shared__ bf16_t Bs[128 * 32];
    const int tid = threadIdx.x;
    const int m0 = blockIdx.x * 128;
    const int n0 = blockIdx.y * 128;
    const int kbase = blockIdx.z * (kiters * 32);
    const int lane = tid & 63;
    const int wv = tid >> 6;
    const int wm = wv >> 1, wn = wv & 1;
    const int r = lane & 15, g = lane >> 4;

    spart += (size_t)blockIdx.z * NQ * NC;

    f32x4 acc[4][4];
    #pragma unroll
    for (int i = 0; i < 4; ++i)
        #pragma unroll
        for (int j = 0; j < 4; ++j)
            acc[i][j] = (f32x4){0.f, 0.f, 0.f, 0.f};

    const int arow = tid >> 1;
    const int ah = (tid & 1) * 16;

    for (int it = 0; it < kiters; ++it) {
        const int k0 = kbase + it * 32;
        // ---- stage A: 128x32 fp32 -> bf16 through registers ----
        {
            const float* src = q + (size_t)(m0 + arow) * DD + k0 + ah;
            float4 f0 = *(const float4*)(src);
            float4 f1 = *(const float4*)(src + 4);
            float4 f2 = *(const float4*)(src + 8);
            float4 f3 = *(const float4*)(src + 12);
            bf16x8 w0, w1;
            w0[0] = (bf16_t)f0.x; w0[1] = (bf16_t)f0.y; w0[2] = (bf16_t)f0.z; w0[3] = (bf16_t)f0.w;
            w0[4] = (bf16_t)f1.x; w0[5] = (bf16_t)f1.y; w0[6] = (bf16_t)f1.z; w0[7] = (bf16_t)f1.w;
            w1[0] = (bf16_t)f2.x; w1[1] = (bf16_t)f2.y; w1[2] = (bf16_t)f2.z; w1[3] = (bf16_t)f2.w;
            w1[4] = (bf16_t)f3.x; w1[5] = (bf16_t)f3.y; w1[6] = (bf16_t)f3.z; w1[7] = (bf16_t)f3.w;
            *(bf16x8*)(As + arow * 32 + ah)     = w0;
            *(bf16x8*)(As + arow * 32 + ah + 8) = w1;
        }
        // ---- stage B: 128x32 bf16 via global_load_lds (16B/lane) ----
        {
            #pragma unroll
            for (int p = 0; p < 2; ++p) {
                int ci = p * 256 + tid;                     // 16B chunk index
                const bf16_t* src = protos + (size_t)(n0 + (ci >> 2)) * DD + k0 + (ci & 3) * 8;
                bf16_t* dst = Bs + ((size_t)(p * 256 + wv * 64)) * 8; // wave-uniform base
                __builtin_amdgcn_global_load_lds(
                    (const __attribute__((address_space(1))) void*)src,
                    (__attribute__((address_space(3))) void*)dst, 16, 0, 0);
            }
        }
        __syncthreads();
        // ---- fragments + MFMA ----
        bf16x8 af[4], bfr[4];
        #pragma unroll
        for (int mi = 0; mi < 4; ++mi)
            af[mi] = *(const bf16x8*)(As + (wm * 64 + mi * 16 + r) * 32 + g * 8);
        #pragma unroll
        for (int ni = 0; ni < 4; ++ni)
            bfr[ni] = *(const bf16x8*)(Bs + (wn * 64 + ni * 16 + r) * 32 + g * 8);
        #pragma unroll
        for (int mi = 0; mi < 4; ++mi)
            #pragma unroll
            for (int ni = 0; ni < 4; ++ni)
                acc[mi][ni] = __builtin_amdgcn_mfma_f32_16x16x32_bf16(
                    af[mi], bfr[ni], acc[mi][ni], 0, 0, 0);
        __syncthreads();
    }
    // ---- epilogue: C/D layout col=lane&15, row=(lane>>4)*4+reg ----
    #pragma unroll
    for (int mi = 0; mi < 4; ++mi) {
        #pragma unroll
        for (int ni = 0; ni < 4; ++ni) {
            int row = m0 + wm * 64 + mi * 16 + g * 4;
            int col = n0 + wn * 64 + ni * 16 + r;
            #pragma unroll
            for (int j = 0; j < 4; ++j)
                spart[(size_t)(row + j) * NC + col] = acc[mi][ni][j];
        }
    }
}

// ---------------------------------------------------------------------------
// Kernel 3: sum K-split partials, logits = 2*dot - p2, row log_softmax.
// One wave per row (512 cols = 8 floats/lane).
// ---------------------------------------------------------------------------
__global__ __launch_bounds__(256) void logsoftmax_kernel(
    const float* __restrict__ s, const float* __restrict__ p2,
    float* __restrict__ out, int nsplit)
{
    const int row  = blockIdx.x * 4 + (threadIdx.x >> 6);
    const int lane = threadIdx.x & 63;
    const size_t off = (size_t)row * NC + lane * 8;
    const size_t stride = (size_t)NQ * NC;

    float v[8];
    float4 a = *(const float4*)(s + off);
    float4 b = *(const float4*)(s + off + 4);
    v[0]=a.x; v[1]=a.y; v[2]=a.z; v[3]=a.w; v[4]=b.x; v[5]=b.y; v[6]=b.z; v[7]=b.w;
    for (int t = 1; t < nsplit; ++t) {
        float4 c = *(const float4*)(s + (size_t)t * stride + off);
        float4 d = *(const float4*)(s + (size_t)t * stride + off + 4);
        v[0]+=c.x; v[1]+=c.y; v[2]+=c.z; v[3]+=c.w;
        v[4]+=d.x; v[5]+=d.y; v[6]+=d.z; v[7]+=d.w;
    }
    float4 pa = *(const float4*)(p2 + lane * 8);
    float4 pb = *(const float4*)(p2 + lane * 8 + 4);
    v[0] = 2.f*v[0] - pa.x; v[1] = 2.f*v[1] - pa.y;
    v[2] = 2.f*v[2] - pa.z; v[3] = 2.f*v[3] - pa.w;
    v[4] = 2.f*v[4] - pb.x; v[5] = 2.f*v[5] - pb.y;
    v[6] = 2.f*v[6] - pb.z; v[7] = 2.f*v[7] - pb.w;

    float mx = v[0];
    #pragma unroll
    for (int i = 1; i < 8; ++i) mx = fmaxf(mx, v[i]);
    #pragma unroll
    for (int o = 32; o > 0; o >>= 1) mx = fmaxf(mx, __shfl_xor(mx, o));
    float se = 0.f;
    #pragma unroll
    for (int i = 0; i < 8; ++i) se += expf(v[i] - mx);
    #pragma unroll
    for (int o = 32; o > 0; o >>= 1) se += __shfl_xor(se, o);
    float lz = mx + logf(se);

    float4 o1 = {v[0]-lz, v[1]-lz, v[2]-lz, v[3]-lz};
    float4 o2 = {v[4]-lz, v[5]-lz, v[6]-lz, v[7]-lz};
    *(float4*)(out + off)     = o1;
    *(float4*)(out + off + 4) = o2;
}

// ---------------------------------------------------------------------------
extern "C" void kernel_launch(void* const* d_in, const int* in_sizes, int n_in,
                              void* d_out, int out_size, void* d_ws, size_t ws_size,
                              hipStream_t stream)
{
    const float* sup = (const float*)d_in[0];   // [2560,64,5,5]
    const float* qry = (const float*)d_in[1];   // [8192,64,5,5]
    const int*   lab = (const int*)d_in[2];     // [2560]
    float* out = (float*)d_out;                 // [8192,512]

    char* ws = (char*)d_ws;
    bf16_t* protos = (bf16_t*)ws;                   // 512*1600*2 = 1,638,400 B
    float*  p2     = (float*)(ws + 1638400);        // 2 KB
    float*  sbuf   = (float*)(ws + 1703936);        // KS * 16 MiB partials

    const size_t per = (size_t)NQ * NC * 4;
    int KS;
    if      (ws_size >= 1703936 + 5 * per) KS = 5;
    else if (ws_size >= 1703936 + 2 * per) KS = 2;
    else                                   KS = 1;
    const int kiters = 50 / KS;   // K=1600, BK=32 -> 50 total iters

    proto_kernel<<<512, 256, 0, stream>>>(sup, lab, protos, p2);
    gemm_kernel<<<dim3(64, 4, KS), 256, 0, stream>>>(qry, protos, sbuf, kiters);
    logsoftmax_kernel<<<NQ / 4, 256, 0, stream>>>(sbuf, p2, out, KS);
}

// Round 2
// 60.814 us; speedup vs baseline: 1.1513x; 1.1513x over previous
//
#include <hip/hip_runtime.h>
#include <hip/hip_bf16.h>
#include <cstdint>
#include <cstddef>

#define NS 2560
#define NQ 8192
#define NC 512
#define DD 1600

typedef __bf16 bf16_t;
typedef __bf16 bf16x4 __attribute__((ext_vector_type(4)));
typedef __bf16 bf16x8 __attribute__((ext_vector_type(8)));
typedef float f32x4 __attribute__((ext_vector_type(4)));

// ---------------------------------------------------------------------------
// Kernel 1: class-mean prototypes (bf16) + ||p||^2 (fp32). One block per class.
// ---------------------------------------------------------------------------
__global__ __launch_bounds__(256) void proto_kernel(
    const float* __restrict__ sup, const int* __restrict__ lab,
    bf16_t* __restrict__ protos, float* __restrict__ p2)
{
    const int m   = blockIdx.x;
    const int tid = threadIdx.x;
    __shared__ int   idxs[32];
    __shared__ int   cnt;
    __shared__ float wsum[4];
    if (tid == 0) cnt = 0;
    __syncthreads();
    for (int i = tid; i < NS; i += 256) {
        if (lab[i] == m) {
            int p = atomicAdd(&cnt, 1);
            if (p < 32) idxs[p] = i;
        }
    }
    __syncthreads();
    int n = cnt < 32 ? cnt : 32;
    if (tid == 0 && n > 1) {                       // deterministic order
        for (int a = 1; a < n; ++a) {
            int key = idxs[a]; int b = a - 1;
            while (b >= 0 && idxs[b] > key) { idxs[b+1] = idxs[b]; --b; }
            idxs[b+1] = key;
        }
    }
    __syncthreads();

    float acc[7];
    #pragma unroll
    for (int u = 0; u < 7; ++u) acc[u] = 0.f;
    for (int t = 0; t < n; ++t) {
        const float* src = sup + (size_t)idxs[t] * DD;
        #pragma unroll
        for (int u = 0; u < 7; ++u) {
            int j = tid + u * 256;
            if (j < DD) acc[u] += src[j];
        }
    }
    float inv = (n > 0) ? 1.f / (float)n : 0.f;
    float psq = 0.f;
    #pragma unroll
    for (int u = 0; u < 7; ++u) {
        int j = tid + u * 256;
        if (j < DD) {
            float p = acc[u] * inv;
            bf16_t pb = (bf16_t)p;
            protos[(size_t)m * DD + j] = pb;
            float pf = (float)pb;
            psq += pf * pf;
        }
    }
    #pragma unroll
    for (int o = 32; o > 0; o >>= 1) psq += __shfl_xor(psq, o);
    int lane = tid & 63, wid = tid >> 6;
    if (lane == 0) wsum[wid] = psq;
    __syncthreads();
    if (tid == 0) p2[m] = wsum[0] + wsum[1] + wsum[2] + wsum[3];
}

// ---------------------------------------------------------------------------
// Kernel 2 (fused): per block, 32 query rows x ALL 512 classes, K=1600,
// bf16 MFMA with XOR-swizzled LDS, then log_softmax in the epilogue.
// 8 waves; wave w owns cols [w*64, w*64+64). BK=64.
//   LDS swizzle: byte ^= ((row&7)<<4) on 128B rows -> 2-way conflicts (free).
//   B staged via global_load_lds with PRE-SWIZZLED global source (linear dest).
//   A (fp32 query) reg-staged with fused fp32->bf16, swizzled ds_write.
// log_softmax(2*q.p - |p|^2) == reference (||q||^2 is shift-invariant).
// ---------------------------------------------------------------------------
__global__ __launch_bounds__(512, 4) void fused_kernel(
    const float* __restrict__ q, const bf16_t* __restrict__ protos,
    const float* __restrict__ p2, float* __restrict__ out)
{
    __shared__ bf16_t As[32 * 64];    // 4 KB
    __shared__ bf16_t Bs[512 * 64];   // 64 KB

    const int tid  = threadIdx.x;
    const int lane = tid & 63;
    const int wid  = tid >> 6;        // wave = column strip 0..7
    const int r    = lane & 15;
    const int g    = lane >> 4;
    const int m0   = blockIdx.x * 32;

    float p2c[4];
    #pragma unroll
    for (int ni = 0; ni < 4; ++ni) p2c[ni] = p2[wid * 64 + ni * 16 + r];

    f32x4 acc[2][4];
    #pragma unroll
    for (int mi = 0; mi < 2; ++mi)
        #pragma unroll
        for (int ni = 0; ni < 4; ++ni)
            acc[mi][ni] = (f32x4){0.f, 0.f, 0.f, 0.f};

    const int arow = tid >> 4;        // 0..31
    const int acg  = tid & 15;        // 4-float column group

    for (int it = 0; it < 25; ++it) {
        const int k0 = it * 64;
        // ---- stage A: 32x64 fp32 -> bf16, swizzled ds_write ----
        {
            float4 f = *(const float4*)(q + (size_t)(m0 + arow) * DD + k0 + acg * 4);
            bf16x4 w;
            w[0] = (bf16_t)f.x; w[1] = (bf16_t)f.y; w[2] = (bf16_t)f.z; w[3] = (bf16_t)f.w;
            int ab = (arow * 128 + acg * 8) ^ ((arow & 7) << 4);
            *(bf16x4*)((char*)As + ab) = w;
        }
        // ---- stage B: 512x64 bf16 via global_load_lds, pre-swizzled src ----
        #pragma unroll
        for (int p = 0; p < 8; ++p) {
            int idx = p * 512 + tid;              // 16B granule index
            int row = idx >> 3;
            int gs  = (idx & 7) ^ (row & 7);      // inverse swizzle on source
            const bf16_t* src = protos + (size_t)row * DD + k0 + gs * 8;
            char* dst = (char*)Bs + (size_t)(p * 512 + wid * 64) * 16;
            __builtin_amdgcn_global_load_lds(
                (const __attribute__((address_space(1))) void*)src,
                (__attribute__((address_space(3))) void*)dst, 16, 0, 0);
        }
        __syncthreads();
        // ---- fragments + MFMA (2 K-slices of 32) ----
        #pragma unroll
        for (int kk = 0; kk < 2; ++kk) {
            bf16x8 af[2], bfr[4];
            #pragma unroll
            for (int mi = 0; mi < 2; ++mi) {
                int ab = ((mi * 16 + r) * 128 + kk * 64 + g * 16) ^ ((r & 7) << 4);
                af[mi] = *(const bf16x8*)((const char*)As + ab);
            }
            #pragma unroll
            for (int ni = 0; ni < 4; ++ni) {
                int c  = wid * 64 + ni * 16 + r;
                int bb = (c * 128 + kk * 64 + g * 16) ^ ((r & 7) << 4);
                bfr[ni] = *(const bf16x8*)((const char*)Bs + bb);
            }
            #pragma unroll
            for (int mi = 0; mi < 2; ++mi)
                #pragma unroll
                for (int ni = 0; ni < 4; ++ni)
                    acc[mi][ni] = __builtin_amdgcn_mfma_f32_16x16x32_bf16(
                        af[mi], bfr[ni], acc[mi][ni], 0, 0, 0);
        }
        __syncthreads();
    }

    // ---- logits = 2*dot - |p|^2 ----
    #pragma unroll
    for (int mi = 0; mi < 2; ++mi)
        #pragma unroll
        for (int ni = 0; ni < 4; ++ni)
            #pragma unroll
            for (int j = 0; j < 4; ++j)
                acc[mi][ni][j] = 2.f * acc[mi][ni][j] - p2c[ni];

    // ---- fused log_softmax over 512 cols (LDS scratch overlays As) ----
    float* red  = (float*)As;     // [32][8]
    float* gmax = red + 256;      // [32]
    float* lse  = gmax + 32;      // [32]

    // pass 1: row max
    float rmax[2][4];
    #pragma unroll
    for (int mi = 0; mi < 2; ++mi)
        #pragma unroll
        for (int j = 0; j < 4; ++j) {
            float m = acc[mi][0][j];
            #pragma unroll
            for (int ni = 1; ni < 4; ++ni) m = fmaxf(m, acc[mi][ni][j]);
            rmax[mi][j] = m;
        }
    #pragma unroll
    for (int o = 1; o < 16; o <<= 1)
        #pragma unroll
        for (int mi = 0; mi < 2; ++mi)
            #pragma unroll
            for (int j = 0; j < 4; ++j)
                rmax[mi][j] = fmaxf(rmax[mi][j], __shfl_xor(rmax[mi][j], o));
    if (r == 0) {
        #pragma unroll
        for (int mi = 0; mi < 2; ++mi)
            #pragma unroll
            for (int j = 0; j < 4; ++j)
                red[(mi * 16 + g * 4 + j) * 8 + wid] = rmax[mi][j];
    }
    __syncthreads();
    if (tid < 32) {
        float m = red[tid * 8];
        #pragma unroll
        for (int w = 1; w < 8; ++w) m = fmaxf(m, red[tid * 8 + w]);
        gmax[tid] = m;
    }
    __syncthreads();

    // pass 2: sum exp
    float rsum[2][4];
    #pragma unroll
    for (int mi = 0; mi < 2; ++mi)
        #pragma unroll
        for (int j = 0; j < 4; ++j) {
            float gm = gmax[mi * 16 + g * 4 + j];
            float s = 0.f;
            #pragma unroll
            for (int ni = 0; ni < 4; ++ni) s += expf(acc[mi][ni][j] - gm);
            rsum[mi][j] = s;
        }
    #pragma unroll
    for (int o = 1; o < 16; o <<= 1)
        #pragma unroll
        for (int mi = 0; mi < 2; ++mi)
            #pragma unroll
            for (int j = 0; j < 4; ++j)
                rsum[mi][j] += __shfl_xor(rsum[mi][j], o);
    if (r == 0) {
        #pragma unroll
        for (int mi = 0; mi < 2; ++mi)
            #pragma unroll
            for (int j = 0; j < 4; ++j)
                red[(mi * 16 + g * 4 + j) * 8 + wid] = rsum[mi][j];
    }
    __syncthreads();
    if (tid < 32) {
        float s = 0.f;
        #pragma unroll
        for (int w = 0; w < 8; ++w) s += red[tid * 8 + w];
        lse[tid] = gmax[tid] + logf(s);
    }
    __syncthreads();

    // ---- write output ----
    #pragma unroll
    for (int mi = 0; mi < 2; ++mi) {
        #pragma unroll
        for (int j = 0; j < 4; ++j) {
            float l = lse[mi * 16 + g * 4 + j];
            size_t rowoff = (size_t)(m0 + mi * 16 + g * 4 + j) * NC;
            #pragma unroll
            for (int ni = 0; ni < 4; ++ni)
                out[rowoff + wid * 64 + ni * 16 + r] = acc[mi][ni][j] - l;
        }
    }
}

// ---------------------------------------------------------------------------
extern "C" void kernel_launch(void* const* d_in, const int* in_sizes, int n_in,
                              void* d_out, int out_size, void* d_ws, size_t ws_size,
                              hipStream_t stream)
{
    const float* sup = (const float*)d_in[0];   // [2560,64,5,5]
    const float* qry = (const float*)d_in[1];   // [8192,64,5,5]
    const int*   lab = (const int*)d_in[2];     // [2560]
    float* out = (float*)d_out;                 // [8192,512]

    char* ws = (char*)d_ws;
    bf16_t* protos = (bf16_t*)ws;               // 512*1600*2 = 1,638,400 B
    float*  p2     = (float*)(ws + 1638400);    // 2 KB

    proto_kernel<<<NC, 256, 0, stream>>>(sup, lab, protos, p2);
    fused_kernel<<<NQ / 32, 512, 0, stream>>>(qry, protos, p2, out);
}

// Round 3
// 54.763 us; speedup vs baseline: 1.2785x; 1.1105x over previous
//
#include <hip/hip_runtime.h>
#include <hip/hip_bf16.h>
#include <cstdint>
#include <cstddef>

#define NS 2560
#define NQ 8192
#define NC 512
#define DD 1600

typedef __bf16 bf16_t;
typedef __bf16 bf16x4 __attribute__((ext_vector_type(4)));
typedef __bf16 bf16x8 __attribute__((ext_vector_type(8)));
typedef float f32x4 __attribute__((ext_vector_type(4)));

// ---------------------------------------------------------------------------
// Kernel 1: class-mean prototypes (bf16) + ||p||^2 (fp32). One block per class.
// ---------------------------------------------------------------------------
__global__ __launch_bounds__(256) void proto_kernel(
    const float* __restrict__ sup, const int* __restrict__ lab,
    bf16_t* __restrict__ protos, float* __restrict__ p2)
{
    const int m   = blockIdx.x;
    const int tid = threadIdx.x;
    __shared__ int   idxs[32];
    __shared__ int   cnt;
    __shared__ float wsum[4];
    if (tid == 0) cnt = 0;
    __syncthreads();
    for (int i = tid; i < NS; i += 256) {
        if (lab[i] == m) {
            int p = atomicAdd(&cnt, 1);
            if (p < 32) idxs[p] = i;
        }
    }
    __syncthreads();
    int n = cnt < 32 ? cnt : 32;
    if (tid == 0 && n > 1) {                       // deterministic order
        for (int a = 1; a < n; ++a) {
            int key = idxs[a]; int b = a - 1;
            while (b >= 0 && idxs[b] > key) { idxs[b+1] = idxs[b]; --b; }
            idxs[b+1] = key;
        }
    }
    __syncthreads();

    float acc[7];
    #pragma unroll
    for (int u = 0; u < 7; ++u) acc[u] = 0.f;
    for (int t = 0; t < n; ++t) {
        const float* src = sup + (size_t)idxs[t] * DD;
        #pragma unroll
        for (int u = 0; u < 7; ++u) {
            int j = tid + u * 256;
            if (j < DD) acc[u] += src[j];
        }
    }
    float inv = (n > 0) ? 1.f / (float)n : 0.f;
    float psq = 0.f;
    #pragma unroll
    for (int u = 0; u < 7; ++u) {
        int j = tid + u * 256;
        if (j < DD) {
            float p = acc[u] * inv;
            bf16_t pb = (bf16_t)p;
            protos[(size_t)m * DD + j] = pb;
            float pf = (float)pb;
            psq += pf * pf;
        }
    }
    #pragma unroll
    for (int o = 32; o > 0; o >>= 1) psq += __shfl_xor(psq, o);
    int lane = tid & 63, wid = tid >> 6;
    if (lane == 0) wsum[wid] = psq;
    __syncthreads();
    if (tid == 0) p2[m] = wsum[0] + wsum[1] + wsum[2] + wsum[3];
}

// ---------------------------------------------------------------------------
// B staging: 512x64 bf16 tile via global_load_lds (16B granules), linear LDS
// dest + pre-swizzled global source (inverse of the read-side XOR swizzle).
// ---------------------------------------------------------------------------
__device__ __forceinline__ void stage_B(const bf16_t* __restrict__ protos,
                                        bf16_t* bbuf, int k0, int tid, int wid)
{
    #pragma unroll
    for (int p = 0; p < 8; ++p) {
        int idx = p * 512 + tid;              // 16B granule index
        int row = idx >> 3;
        int gs  = (idx & 7) ^ (row & 7);      // inverse swizzle on source
        const bf16_t* src = protos + (size_t)row * DD + k0 + gs * 8;
        char* dst = (char*)bbuf + (size_t)(p * 512 + wid * 64) * 16;
        __builtin_amdgcn_global_load_lds(
            (const __attribute__((address_space(1))) void*)src,
            (__attribute__((address_space(3))) void*)dst, 16, 0, 0);
    }
}

// ---------------------------------------------------------------------------
// Kernel 2 (fused, 2-phase pipelined): 32 query rows x ALL 512 classes per
// block, K=1600 in 25 steps of BK=64. Double-buffered B (2x64KB) and A
// (2x4KB) in dynamic LDS (139264 B). Per iter: issue next A (reg) + next B
// (global_load_lds) FIRST, compute current tile, convert+ds_write next A,
// then one __syncthreads (its mandatory vmcnt(0) drain is the pipeline wait).
// Epilogue: logits = 2*dot - |p|^2, row log_softmax across 8 waves.
// ---------------------------------------------------------------------------
__global__ __launch_bounds__(512, 2) void fused_kernel(
    const float* __restrict__ q, const bf16_t* __restrict__ protos,
    const float* __restrict__ p2, float* __restrict__ out)
{
    extern __shared__ char smem[];
    bf16_t* Bs0 = (bf16_t*)(smem);
    bf16_t* Bs1 = (bf16_t*)(smem + 65536);
    bf16_t* As0 = (bf16_t*)(smem + 131072);
    bf16_t* As1 = (bf16_t*)(smem + 135168);

    const int tid  = threadIdx.x;
    const int lane = tid & 63;
    const int wid  = tid >> 6;        // wave = 64-col strip 0..7
    const int r    = lane & 15;
    const int g    = lane >> 4;
    const int m0   = blockIdx.x * 32;

    float p2c[4];
    #pragma unroll
    for (int ni = 0; ni < 4; ++ni) p2c[ni] = p2[wid * 64 + ni * 16 + r];

    f32x4 acc[2][4];
    #pragma unroll
    for (int mi = 0; mi < 2; ++mi)
        #pragma unroll
        for (int ni = 0; ni < 4; ++ni)
            acc[mi][ni] = (f32x4){0.f, 0.f, 0.f, 0.f};

    const int arow = tid >> 4;        // 0..31
    const int acg  = tid & 15;        // 4-float column group
    const float* aptr = q + (size_t)(m0 + arow) * DD + acg * 4;
    const int    aoff = (arow * 128 + acg * 8) ^ ((arow & 7) << 4);

    // ---- prologue: stage tile 0 ----
    {
        float4 f = *(const float4*)(aptr);
        stage_B(protos, Bs0, 0, tid, wid);
        bf16x4 w;
        w[0] = (bf16_t)f.x; w[1] = (bf16_t)f.y; w[2] = (bf16_t)f.z; w[3] = (bf16_t)f.w;
        *(bf16x4*)((char*)As0 + aoff) = w;
        __syncthreads();
    }

    for (int t = 0; t < 25; ++t) {
        const int cur = t & 1;
        bf16_t* bs  = cur ? Bs1 : Bs0;
        bf16_t* as  = cur ? As1 : As0;
        bf16_t* bsn = cur ? Bs0 : Bs1;
        bf16_t* asn = cur ? As0 : As1;
        const bool pre = (t < 24);

        // ---- issue next-tile loads (A to regs first: its use waits vmcnt(8)) ----
        float4 fA;
        if (pre) {
            fA = *(const float4*)(aptr + (t + 1) * 64);
            stage_B(protos, bsn, (t + 1) * 64, tid, wid);
        }

        // ---- compute current tile: 2 K-slices of 32 ----
        #pragma unroll
        for (int kk = 0; kk < 2; ++kk) {
            bf16x8 af[2], bfr[4];
            #pragma unroll
            for (int mi = 0; mi < 2; ++mi) {
                int ab = ((mi * 16 + r) * 128 + kk * 64 + g * 16) ^ ((r & 7) << 4);
                af[mi] = *(const bf16x8*)((const char*)as + ab);
            }
            #pragma unroll
            for (int ni = 0; ni < 4; ++ni) {
                int c  = wid * 64 + ni * 16 + r;
                int bb = (c * 128 + kk * 64 + g * 16) ^ ((r & 7) << 4);
                bfr[ni] = *(const bf16x8*)((const char*)bs + bb);
            }
            #pragma unroll
            for (int mi = 0; mi < 2; ++mi)
                #pragma unroll
                for (int ni = 0; ni < 4; ++ni)
                    acc[mi][ni] = __builtin_amdgcn_mfma_f32_16x16x32_bf16(
                        af[mi], bfr[ni], acc[mi][ni], 0, 0, 0);
        }

        // ---- convert + write next A tile (other buffer; pre-barrier is safe) ----
        if (pre) {
            bf16x4 w;
            w[0] = (bf16_t)fA.x; w[1] = (bf16_t)fA.y;
            w[2] = (bf16_t)fA.z; w[3] = (bf16_t)fA.w;
            *(bf16x4*)((char*)asn + aoff) = w;
        }
        // mandatory vmcnt(0)+lgkmcnt(0) drain here completes next B tile
        __syncthreads();
    }

    // ---- logits = 2*dot - |p|^2 ----
    #pragma unroll
    for (int mi = 0; mi < 2; ++mi)
        #pragma unroll
        for (int ni = 0; ni < 4; ++ni)
            #pragma unroll
            for (int j = 0; j < 4; ++j)
                acc[mi][ni][j] = 2.f * acc[mi][ni][j] - p2c[ni];

    // ---- fused log_softmax over 512 cols (scratch overlays Bs0; loop ended
    //      with __syncthreads so all LDS reads are done) ----
    float* red  = (float*)smem;   // [32][8]
    float* gmax = red + 256;      // [32]
    float* lse  = gmax + 32;      // [32]

    float rmax[2][4];
    #pragma unroll
    for (int mi = 0; mi < 2; ++mi)
        #pragma unroll
        for (int j = 0; j < 4; ++j) {
            float m = acc[mi][0][j];
            #pragma unroll
            for (int ni = 1; ni < 4; ++ni) m = fmaxf(m, acc[mi][ni][j]);
            rmax[mi][j] = m;
        }
    #pragma unroll
    for (int o = 1; o < 16; o <<= 1)
        #pragma unroll
        for (int mi = 0; mi < 2; ++mi)
            #pragma unroll
            for (int j = 0; j < 4; ++j)
                rmax[mi][j] = fmaxf(rmax[mi][j], __shfl_xor(rmax[mi][j], o));
    if (r == 0) {
        #pragma unroll
        for (int mi = 0; mi < 2; ++mi)
            #pragma unroll
            for (int j = 0; j < 4; ++j)
                red[(mi * 16 + g * 4 + j) * 8 + wid] = rmax[mi][j];
    }
    __syncthreads();
    if (tid < 32) {
        float m = red[tid * 8];
        #pragma unroll
        for (int w = 1; w < 8; ++w) m = fmaxf(m, red[tid * 8 + w]);
        gmax[tid] = m;
    }
    __syncthreads();

    float rsum[2][4];
    #pragma unroll
    for (int mi = 0; mi < 2; ++mi)
        #pragma unroll
        for (int j = 0; j < 4; ++j) {
            float gm = gmax[mi * 16 + g * 4 + j];
            float s = 0.f;
            #pragma unroll
            for (int ni = 0; ni < 4; ++ni) s += expf(acc[mi][ni][j] - gm);
            rsum[mi][j] = s;
        }
    #pragma unroll
    for (int o = 1; o < 16; o <<= 1)
        #pragma unroll
        for (int mi = 0; mi < 2; ++mi)
            #pragma unroll
            for (int j = 0; j < 4; ++j)
                rsum[mi][j] += __shfl_xor(rsum[mi][j], o);
    if (r == 0) {
        #pragma unroll
        for (int mi = 0; mi < 2; ++mi)
            #pragma unroll
            for (int j = 0; j < 4; ++j)
                red[(mi * 16 + g * 4 + j) * 8 + wid] = rsum[mi][j];
    }
    __syncthreads();
    if (tid < 32) {
        float s = 0.f;
        #pragma unroll
        for (int w = 0; w < 8; ++w) s += red[tid * 8 + w];
        lse[tid] = gmax[tid] + logf(s);
    }
    __syncthreads();

    // ---- write output ----
    #pragma unroll
    for (int mi = 0; mi < 2; ++mi) {
        #pragma unroll
        for (int j = 0; j < 4; ++j) {
            float l = lse[mi * 16 + g * 4 + j];
            size_t rowoff = (size_t)(m0 + mi * 16 + g * 4 + j) * NC;
            #pragma unroll
            for (int ni = 0; ni < 4; ++ni)
                out[rowoff + wid * 64 + ni * 16 + r] = acc[mi][ni][j] - l;
        }
    }
}

// ---------------------------------------------------------------------------
extern "C" void kernel_launch(void* const* d_in, const int* in_sizes, int n_in,
                              void* d_out, int out_size, void* d_ws, size_t ws_size,
                              hipStream_t stream)
{
    const float* sup = (const float*)d_in[0];   // [2560,64,5,5]
    const float* qry = (const float*)d_in[1];   // [8192,64,5,5]
    const int*   lab = (const int*)d_in[2];     // [2560]
    float* out = (float*)d_out;                 // [8192,512]

    char* ws = (char*)d_ws;
    bf16_t* protos = (bf16_t*)ws;               // 512*1600*2 = 1,638,400 B
    float*  p2     = (float*)(ws + 1638400);    // 2 KB

    const int smem_bytes = 139264;              // 2x64KB B + 2x4KB A
    hipFuncSetAttribute(reinterpret_cast<const void*>(fused_kernel),
                        hipFuncAttributeMaxDynamicSharedMemorySize, smem_bytes);

    proto_kernel<<<NC, 256, 0, stream>>>(sup, lab, protos, p2);
    fused_kernel<<<NQ / 32, 512, smem_bytes, stream>>>(qry, protos, p2, out);
}